// Round 10
// baseline (392.425 us; speedup 1.0000x reference)
//
#include <hip/hip_runtime.h>
#include <stdint.h>

#define NMEM 50000
#define NTOT 100000
#define DMEM 96
#define DPRV 128
#define IND  128
#define HID  256
#define LATD 64
#define NEDGE 1000000

// counting-sort CSR build params
#define NB   196   // buckets = ceil(NTOT / 512)
#define VSH  9     // 512 vertices per bucket
#define NBV  512
#define EPB  4096  // edges per block in partition passes

// k_prep role split
#define PREP_PCOUNT 245
#define PREP_CANON  418
// k_out role split
#define G3B 1563

typedef __bf16 v8bf  __attribute__((ext_vector_type(8)));
typedef float  f32x4 __attribute__((ext_vector_type(4)));

__device__ __forceinline__ float bf2f(uint32_t u) {
    union { uint32_t u; float f; } x; x.u = u << 16; return x.f;
}
__device__ __forceinline__ uint32_t f2bf(float f) {
    union { float f; uint32_t u; } x; x.f = f;
    uint32_t r = x.u + 0x7fffu + ((x.u >> 16) & 1u);
    return r >> 16;
}
__device__ __forceinline__ int ld_ei(const int* ei, int idx, int i64) {
    return i64 ? ei[2 * idx] : ei[idx];
}

// flags[0]=inputs-are-f32, flags[1]=edge-index-is-int64
__global__ void k_detect(const uint16_t* __restrict__ w1l, const int* __restrict__ ei,
                         int* __restrict__ flags) {
    __shared__ int c1, c2;
    if (threadIdx.x == 0) { c1 = 0; c2 = 0; }
    __syncthreads();
    int big = 0;
    for (int i = threadIdx.x; i < 32768; i += 256) {
        float w = bf2f(w1l[i]);
        if (!(w > -2.0f && w < 2.0f)) big++;
    }
    int zhi = 0;
    for (int j = threadIdx.x; j < 2048; j += 256)
        if (ei[2 * j + 1] == 0) zhi++;
    atomicAdd(&c1, big);
    atomicAdd(&c2, zhi);
    __syncthreads();
    if (threadIdx.x == 0) {
        flags[0] = (c1 > 64) ? 1 : 0;
        flags[1] = (c2 > 1024) ? 1 : 0;
    }
}

// k_prep: role-split merge of {pcount | canon | build_x}.
__global__ __launch_bounds__(256) void k_prep(const void* w1l, const void* w1r,
                                              const void* w2l, const void* w2r,
                                              const void* wd, const void* b1,
                                              const void* b2, const void* bd,
                                              const void* xm, const void* xp,
                                              const int* __restrict__ ei,
                                              uint16_t* __restrict__ dstw,
                                              float* __restrict__ dstb,
                                              uint16_t* __restrict__ Px,
                                              uint16_t* __restrict__ Rx,
                                              int* __restrict__ bcount,
                                              const int* __restrict__ flags) {
    __shared__ int h[NB];
    int bid = blockIdx.x;
    int t = threadIdx.x;
    int f32in = flags[0];
    if (bid < PREP_PCOUNT) {
        for (int i = t; i < NB; i += 256) h[i] = 0;
        __syncthreads();
        int i64 = flags[1];
        int j0 = bid * EPB;
        int jend = min(j0 + EPB, NEDGE);
        for (int j = j0 + t; j < jend; j += 256) {
            int p = ld_ei(ei, j, i64), m = ld_ei(ei, NEDGE + j, i64);
            atomicAdd(&h[(NMEM + m) >> VSH], 1);
            atomicAdd(&h[p >> VSH], 1);
        }
        __syncthreads();
        for (int i = t; i < NB; i += 256) atomicAdd(&bcount[i], h[i]);
        return;
    }
    if (bid < PREP_PCOUNT + PREP_CANON) {
        int g = (bid - PREP_PCOUNT) * 256 + t;
        if (g < 106496) {
            const void* src; int off;
            if (g < 65536) { int n = g >> 8, k = g & 255;
                src = (k < 128) ? w1l : w1r; off = n * 128 + (k & 127); }
            else if (g < 81920) { src = w2l; off = g - 65536; }
            else if (g < 98304) { src = w2r; off = g - 81920; }
            else                { src = wd;  off = g - 98304; }
            dstw[g] = f32in ? (uint16_t)f2bf(((const float*)src)[off])
                            : ((const uint16_t*)src)[off];
        } else if (g < 106944) {
            int o = g - 106496;
            const void* src; int off;
            if (o < 256)      { src = b1; off = o; }
            else if (o < 320) { src = b2; off = o - 256; }
            else              { src = bd; off = o - 320; }
            dstb[o] = f32in ? ((const float*)src)[off] : bf2f(((const uint16_t*)src)[off]);
        }
        return;
    }
    int idx = (bid - PREP_PCOUNT - PREP_CANON) * 256 + t;
    if (idx >= NTOT * 16) return;
    int v = idx >> 4, dblk = idx & 15;
    int d0 = dblk * 8;
    union { uint4 q; uint16_t u[8]; } o;
    if (v < NMEM) {
        if (d0 < DMEM) {
            if (f32in) {
                const float* s = (const float*)xm + (size_t)v * DMEM + d0;
                uint4 lo = *(const uint4*)s;
                uint4 hi = *(const uint4*)(s + 4);
                const float* lf = (const float*)&lo;
                const float* hf = (const float*)&hi;
#pragma unroll
                for (int i = 0; i < 4; i++) o.u[i] = (uint16_t)f2bf(lf[i]);
#pragma unroll
                for (int i = 0; i < 4; i++) o.u[4 + i] = (uint16_t)f2bf(hf[i]);
            } else {
                o.q = *(const uint4*)((const uint16_t*)xm + (size_t)v * DMEM + d0);
            }
        } else {
            o.q = (uint4){0, 0, 0, 0};
        }
    } else {
        int vv = v - NMEM;
        if (f32in) {
            const float* s = (const float*)xp + (size_t)vv * DPRV + d0;
            uint4 lo = *(const uint4*)s;
            uint4 hi = *(const uint4*)(s + 4);
            const float* lf = (const float*)&lo;
            const float* hf = (const float*)&hi;
#pragma unroll
            for (int i = 0; i < 4; i++) o.u[i] = (uint16_t)f2bf(lf[i]);
#pragma unroll
            for (int i = 0; i < 4; i++) o.u[4 + i] = (uint16_t)f2bf(hf[i]);
        } else {
            o.q = *(const uint4*)((const uint16_t*)xp + (size_t)vv * DPRV + d0);
        }
    }
    if (d0 < 64) *(uint4*)(Px + (size_t)v * 64 + d0) = o.q;
    else         *(uint4*)(Rx + (size_t)v * 64 + (d0 - 64)) = o.q;
}

__global__ void k_bscan(const int* __restrict__ bcount, int* __restrict__ bbase,
                        int* __restrict__ bcursor, int* __restrict__ row_start) {
    __shared__ int s[256];
    int t = threadIdx.x;
    int v = (t < NB) ? bcount[t] : 0;
    s[t] = v; __syncthreads();
    for (int off = 1; off < 256; off <<= 1) {
        int x = (t >= off) ? s[t - off] : 0;
        __syncthreads();
        s[t] += x;
        __syncthreads();
    }
    if (t < NB) { bbase[t] = s[t] - v; bcursor[t] = s[t] - v; }
    if (t == 0) { bbase[NB] = 2 * NEDGE; row_start[NTOT] = 2 * NEDGE; }
}

__global__ __launch_bounds__(256) void k_part(const int* __restrict__ ei,
                                              int* __restrict__ bcursor,
                                              uint32_t* __restrict__ part,
                                              const int* __restrict__ flags) {
    __shared__ int h[NB], gb[NB], cur[NB];
    int t = threadIdx.x;
    for (int i = t; i < NB; i += 256) { h[i] = 0; cur[i] = 0; }
    __syncthreads();
    int i64 = flags[1];
    int j0 = blockIdx.x * EPB;
    int jend = min(j0 + EPB, NEDGE);
    for (int j = j0 + t; j < jend; j += 256) {
        int p = ld_ei(ei, j, i64), m = ld_ei(ei, NEDGE + j, i64);
        atomicAdd(&h[(NMEM + m) >> VSH], 1);
        atomicAdd(&h[p >> VSH], 1);
    }
    __syncthreads();
    for (int i = t; i < NB; i += 256) gb[i] = atomicAdd(&bcursor[i], h[i]);
    __syncthreads();
    for (int j = j0 + t; j < jend; j += 256) {
        int p = ld_ei(ei, j, i64), m = ld_ei(ei, NEDGE + j, i64);
        int d1 = NMEM + m;
        int d2 = p;
        int b1 = d1 >> VSH, b2 = d2 >> VSH;
        int r1 = atomicAdd(&cur[b1], 1);
        part[gb[b1] + r1] = ((uint32_t)(d1 & (NBV - 1)) << 17) | (uint32_t)p;
        int r2 = atomicAdd(&cur[b2], 1);
        part[gb[b2] + r2] = ((uint32_t)(d2 & (NBV - 1)) << 17) | (uint32_t)(NMEM + m);
    }
}

__global__ __launch_bounds__(256) void k_sort(const uint32_t* __restrict__ part,
                                              const int* __restrict__ bbase,
                                              int* __restrict__ row_start,
                                              int* __restrict__ colg) {
    __shared__ int sa[NBV], sb[NBV];
    int k = blockIdx.x, t = threadIdx.x;
    int base = bbase[k];
    int cnt  = bbase[k + 1] - base;
    for (int i = t; i < NBV; i += 256) sa[i] = 0;
    __syncthreads();
    for (int i = t; i < cnt; i += 256) {
        uint32_t e = part[base + i];
        atomicAdd(&sa[e >> 17], 1);
    }
    __syncthreads();
    int* src = sa; int* dst = sb;
    for (int off = 1; off < NBV; off <<= 1) {
        for (int i = t; i < NBV; i += 256)
            dst[i] = src[i] + (i >= off ? src[i - off] : 0);
        __syncthreads();
        int* tmp = src; src = dst; dst = tmp;
    }
    for (int i = t; i < NBV; i += 256) {
        int excl = (i > 0) ? src[i - 1] : 0;
        dst[i] = excl;
        int gv = (k << VSH) + i;
        if (gv < NTOT) row_start[gv] = base + excl;
    }
    __syncthreads();
    for (int i = t; i < cnt; i += 256) {
        uint32_t e = part[base + i];
        int dloc = (int)(e >> 17);
        int pos = atomicAdd(&dst[dloc], 1);
        colg[base + pos] = (int)(e & 0x1FFFFu);
    }
}

// agg1: A1[v] = mean over nb(v) of bf16 x rows (in Px|Rx).
// MLP-4 restructure: 16 lanes/vertex (one 16B column chunk each), each lane
// iterates ALL edges stride-1, unroll-4 with 4 accumulator sets -> 4 gathers
// in flight per lane; no cross-lane reduction at all.
__global__ __launch_bounds__(256) void k_agg1(const uint16_t* __restrict__ Px,
                                              const uint16_t* __restrict__ Rx,
                                              const int* __restrict__ row_start,
                                              const int* __restrict__ colg,
                                              uint16_t* __restrict__ A1) {
    int t = threadIdx.x;
    int v = blockIdx.x * 16 + (t >> 4);
    int cg = t & 15;
    const uint16_t* base = (cg < 8) ? Px : Rx;
    int co = (cg & 7) * 8;
    int start = row_start[v], end = row_start[v + 1];
    float a0[8] = {0.f, 0.f, 0.f, 0.f, 0.f, 0.f, 0.f, 0.f};
    float a1[8] = {0.f, 0.f, 0.f, 0.f, 0.f, 0.f, 0.f, 0.f};
    float a2[8] = {0.f, 0.f, 0.f, 0.f, 0.f, 0.f, 0.f, 0.f};
    float a3[8] = {0.f, 0.f, 0.f, 0.f, 0.f, 0.f, 0.f, 0.f};
    int b = start;
    for (; b + 3 < end; b += 4) {
        int s0 = colg[b], s1 = colg[b + 1], s2 = colg[b + 2], s3 = colg[b + 3];
        union { uint4 q; uint16_t u[8]; } f0, f1, f2, f3;
        f0.q = *(const uint4*)(base + (size_t)s0 * 64 + co);
        f1.q = *(const uint4*)(base + (size_t)s1 * 64 + co);
        f2.q = *(const uint4*)(base + (size_t)s2 * 64 + co);
        f3.q = *(const uint4*)(base + (size_t)s3 * 64 + co);
#pragma unroll
        for (int i = 0; i < 8; i++) {
            a0[i] += bf2f(f0.u[i]); a1[i] += bf2f(f1.u[i]);
            a2[i] += bf2f(f2.u[i]); a3[i] += bf2f(f3.u[i]);
        }
    }
    for (; b < end; b++) {
        int s0 = colg[b];
        union { uint4 q; uint16_t u[8]; } f0;
        f0.q = *(const uint4*)(base + (size_t)s0 * 64 + co);
#pragma unroll
        for (int i = 0; i < 8; i++) a0[i] += bf2f(f0.u[i]);
    }
    float inv = 1.0f / (float)max(end - start, 1);
    union { uint4 q; uint16_t u[8]; } o;
#pragma unroll
    for (int i = 0; i < 8; i++)
        o.u[i] = (uint16_t)f2bf((a0[i] + a1[i] + a2[i] + a3[i]) * inv);
    *(uint4*)(A1 + (size_t)v * 128 + cg * 8) = o.q;
}

// GEMM1 (MFMA, N-split register-B, 64-row tile for occupancy):
// block = 64 rows, 4 waves, LDS 33.8KB -> 4 blocks/CU (R4-verified, 64.5us).
__global__ __launch_bounds__(256, 4) void k_gemm1(const uint16_t* __restrict__ A1,
                                                  const uint16_t* __restrict__ canonb,
                                                  const float* __restrict__ biasf,
                                                  uint16_t* __restrict__ P,
                                                  uint16_t* __restrict__ R) {
    __shared__ uint16_t As[64][264];   // 33,792 B; A-panel, then reused as h
    int t = threadIdx.x;
    int w = t >> 6, lane = t & 63;
    int m16 = lane & 15, q = lane >> 4;
    int row0 = blockIdx.x * 64;

    // stage A-panel: 2048 16B chunks, 8 per thread
    uint4 stg[8];
#pragma unroll
    for (int i = 0; i < 8; i++) {
        int c = t + i * 256;
        int row = c >> 5, seg = c & 31;
        int grow = min(row0 + row, NTOT - 1);
        int k0 = seg * 8;
        const uint16_t* src;
        if (k0 < 128)      src = A1 + (size_t)grow * 128 + k0;
        else if (k0 < 192) src = P + (size_t)grow * 64 + (k0 - 128);
        else               src = R + (size_t)grow * 64 + (k0 - 192);
        stg[i] = *(const uint4*)src;
    }
#pragma unroll
    for (int i = 0; i < 8; i++) {
        int c = t + i * 256;
        *(uint4*)&As[c >> 5][(c & 31) * 8] = stg[i];
    }
    __syncthreads();

    // stage 1: h = relu(A @ W1cat^T + b1); 4 passes x 16 cols
    uint32_t hpk[4][4][2];
#pragma unroll
    for (int pn = 0; pn < 4; pn++) {
        int col = w * 64 + pn * 16 + m16;
        v8bf b1[8];
#pragma unroll
        for (int ks = 0; ks < 8; ks++)
            b1[ks] = *(const v8bf*)(canonb + (size_t)col * 256 + ks * 32 + q * 8);
        f32x4 acc[4];
#pragma unroll
        for (int mt = 0; mt < 4; mt++) acc[mt] = (f32x4){0.f, 0.f, 0.f, 0.f};
#pragma unroll
        for (int mt = 0; mt < 4; mt++) {
#pragma unroll
            for (int ks = 0; ks < 8; ks++) {
                v8bf a = *(const v8bf*)&As[mt * 16 + m16][ks * 32 + q * 8];
                acc[mt] = __builtin_amdgcn_mfma_f32_16x16x32_bf16(b1[ks], a, acc[mt], 0, 0, 0);
            }
        }
        int cb = w * 64 + pn * 16 + q * 4;
        f32x4 bb = *(const f32x4*)&biasf[cb];
#pragma unroll
        for (int mt = 0; mt < 4; mt++) {
            float v0 = fmaxf(acc[mt][0] + bb[0], 0.f);
            float v1 = fmaxf(acc[mt][1] + bb[1], 0.f);
            float v2 = fmaxf(acc[mt][2] + bb[2], 0.f);
            float v3 = fmaxf(acc[mt][3] + bb[3], 0.f);
            hpk[pn][mt][0] = f2bf(v0) | (f2bf(v1) << 16);
            hpk[pn][mt][1] = f2bf(v2) | (f2bf(v3) << 16);
        }
        __builtin_amdgcn_sched_barrier(0);
    }
    __syncthreads();   // all As reads done

    // write h into As (uint2 per (pn,mt))
#pragma unroll
    for (int pn = 0; pn < 4; pn++) {
        int cb = w * 64 + pn * 16 + q * 4;
#pragma unroll
        for (int mt = 0; mt < 4; mt++) {
            uint2 v; v.x = hpk[pn][mt][0]; v.y = hpk[pn][mt][1];
            *(uint2*)&As[mt * 16 + m16][cb] = v;
        }
    }
    __syncthreads();

    // stage 2: P = h@W2l^T ; R = h@W2r^T + b2; wave cols [w*32, w*32+32)
    v8bf b2[2][8];
#pragma unroll
    for (int n = 0; n < 2; n++) {
        int c2 = w * 32 + n * 16 + m16;
        const uint16_t* s2 = canonb + (c2 < 64 ? (65536 + c2 * 256) : (81920 + (c2 - 64) * 256));
#pragma unroll
        for (int ks = 0; ks < 8; ks++)
            b2[n][ks] = *(const v8bf*)(s2 + ks * 32 + q * 8);
    }
    f32x4 acc2[4][2];
#pragma unroll
    for (int mt = 0; mt < 4; mt++) {
        acc2[mt][0] = (f32x4){0.f, 0.f, 0.f, 0.f};
        acc2[mt][1] = (f32x4){0.f, 0.f, 0.f, 0.f};
    }
#pragma unroll
    for (int mt = 0; mt < 4; mt++) {
#pragma unroll
        for (int ks = 0; ks < 8; ks++) {
            v8bf hf = *(const v8bf*)&As[mt * 16 + m16][ks * 32 + q * 8];
            acc2[mt][0] = __builtin_amdgcn_mfma_f32_16x16x32_bf16(b2[0][ks], hf, acc2[mt][0], 0, 0, 0);
            acc2[mt][1] = __builtin_amdgcn_mfma_f32_16x16x32_bf16(b2[1][ks], hf, acc2[mt][1], 0, 0, 0);
        }
    }
#pragma unroll
    for (int n = 0; n < 2; n++) {
        int cb = w * 32 + n * 16 + q * 4;
        int isR = cb >= 64;
        int cl = cb - (isR ? 64 : 0);
        f32x4 bb;
        if (isR) bb = *(const f32x4*)&biasf[256 + cl];
        else     bb = (f32x4){0.f, 0.f, 0.f, 0.f};
        uint16_t* dst = isR ? R : P;
#pragma unroll
        for (int mt = 0; mt < 4; mt++) {
            int row = row0 + mt * 16 + m16;
            if (row < NTOT) {
                uint2 v;
                v.x = f2bf(acc2[mt][n][0] + bb[0]) | (f2bf(acc2[mt][n][1] + bb[1]) << 16);
                v.y = f2bf(acc2[mt][n][2] + bb[2]) | (f2bf(acc2[mt][n][3] + bb[3]) << 16);
                *(uint2*)(dst + (size_t)row * 64 + cl) = v;
            }
        }
    }
}

// agg2z: Z[v] = R[v] + mean of P rows over nb(v).
// MLP-4 restructure: 8 lanes/vertex, stride-1 edges, unroll-4, no shuffle.
__global__ __launch_bounds__(256) void k_agg2z(const uint16_t* __restrict__ P,
                                               const uint16_t* __restrict__ R,
                                               const int* __restrict__ row_start,
                                               const int* __restrict__ colg,
                                               uint16_t* __restrict__ Z) {
    int t = threadIdx.x;
    int v = blockIdx.x * 32 + (t >> 3);
    int cg = t & 7;
    int start = row_start[v], end = row_start[v + 1];
    float a0[8] = {0.f, 0.f, 0.f, 0.f, 0.f, 0.f, 0.f, 0.f};
    float a1[8] = {0.f, 0.f, 0.f, 0.f, 0.f, 0.f, 0.f, 0.f};
    float a2[8] = {0.f, 0.f, 0.f, 0.f, 0.f, 0.f, 0.f, 0.f};
    float a3[8] = {0.f, 0.f, 0.f, 0.f, 0.f, 0.f, 0.f, 0.f};
    int b = start;
    for (; b + 3 < end; b += 4) {
        int s0 = colg[b], s1 = colg[b + 1], s2 = colg[b + 2], s3 = colg[b + 3];
        union { uint4 q; uint16_t u[8]; } f0, f1, f2, f3;
        f0.q = *(const uint4*)(P + (size_t)s0 * 64 + cg * 8);
        f1.q = *(const uint4*)(P + (size_t)s1 * 64 + cg * 8);
        f2.q = *(const uint4*)(P + (size_t)s2 * 64 + cg * 8);
        f3.q = *(const uint4*)(P + (size_t)s3 * 64 + cg * 8);
#pragma unroll
        for (int i = 0; i < 8; i++) {
            a0[i] += bf2f(f0.u[i]); a1[i] += bf2f(f1.u[i]);
            a2[i] += bf2f(f2.u[i]); a3[i] += bf2f(f3.u[i]);
        }
    }
    for (; b < end; b++) {
        int s0 = colg[b];
        union { uint4 q; uint16_t u[8]; } f0;
        f0.q = *(const uint4*)(P + (size_t)s0 * 64 + cg * 8);
#pragma unroll
        for (int i = 0; i < 8; i++) a0[i] += bf2f(f0.u[i]);
    }
    float inv = 1.0f / (float)max(end - start, 1);
    union { uint4 q; uint16_t u[8]; } rr, o;
    rr.q = *(const uint4*)(R + (size_t)v * 64 + cg * 8);
#pragma unroll
    for (int i = 0; i < 8; i++)
        o.u[i] = (uint16_t)f2bf((a0[i] + a1[i] + a2[i] + a3[i]) * inv + bf2f(rr.u[i]));
    *(uint4*)(Z + (size_t)v * 64 + cg * 8) = o.q;
}

// k_out: role-split merge of {gemm3 | logits}.
__global__ __launch_bounds__(256, 4) void k_out(const int* __restrict__ ei,
                                                const uint16_t* __restrict__ Z,
                                                const uint16_t* __restrict__ canonb,
                                                const float* __restrict__ biasf,
                                                float* __restrict__ outf,
                                                const int* __restrict__ flags) {
    int bid = blockIdx.x;
    if (bid < G3B) {
        int wave = threadIdx.x >> 6, lane = threadIdx.x & 63;
        int m16 = lane & 15, quad = lane >> 4;
        int row0 = (bid * 4 + wave) * 16;
        int arow = min(row0 + m16, NTOT - 1);
        v8bf a0 = *(const v8bf*)(Z + (size_t)arow * 64 + quad * 8);
        v8bf a1 = *(const v8bf*)(Z + (size_t)arow * 64 + 32 + quad * 8);
        v8bf b0[8], b1[8];
#pragma unroll
        for (int nt = 0; nt < 8; nt++) {
            b0[nt] = *(const v8bf*)(canonb + 98304 + (size_t)(nt * 16 + m16) * 64 + quad * 8);
            b1[nt] = *(const v8bf*)(canonb + 98304 + (size_t)(nt * 16 + m16) * 64 + 32 + quad * 8);
        }
        f32x4 acc[8];
#pragma unroll
        for (int i = 0; i < 8; i++) acc[i] = (f32x4){0.f, 0.f, 0.f, 0.f};
#pragma unroll
        for (int nt = 0; nt < 8; nt++) {
            acc[nt] = __builtin_amdgcn_mfma_f32_16x16x32_bf16(a0, b0[nt], acc[nt], 0, 0, 0);
            acc[nt] = __builtin_amdgcn_mfma_f32_16x16x32_bf16(a1, b1[nt], acc[nt], 0, 0, 0);
        }
#pragma unroll
        for (int nt = 0; nt < 8; nt++) {
            int col = nt * 16 + m16;
            float bia = biasf[320 + col];
#pragma unroll
            for (int r = 0; r < 4; r++) {
                int row = row0 + quad * 4 + r;
                if (row < NTOT) outf[(size_t)row * 128 + col] = acc[nt][r] + bia;
            }
        }
        return;
    }
    int t = (bid - G3B) * 256 + threadIdx.x;
    int j = t >> 3, sub = t & 7;
    if (j >= NEDGE) return;
    int i64 = flags[1];
    int p = ld_ei(ei, j, i64), m = ld_ei(ei, NEDGE + j, i64);
    union { uint4 q; uint16_t u[8]; } a, b;
    a.q = *(const uint4*)(Z + (size_t)(NMEM + p) * 64 + sub * 8);
    b.q = *(const uint4*)(Z + (size_t)m * 64 + sub * 8);
    float d = 0.f;
#pragma unroll
    for (int i = 0; i < 8; i++) d += bf2f(a.u[i]) * bf2f(b.u[i]);
    d += __shfl_xor(d, 1);
    d += __shfl_xor(d, 2);
    d += __shfl_xor(d, 4);
    if (sub == 0) outf[12800000 + j] = d;
}

// Sentinel path (ws too small).
__global__ void k_zero_out(float* __restrict__ out, int n4) {
    int i = blockIdx.x * 256 + threadIdx.x;
    if (i < n4) ((uint4*)out)[i] = (uint4){0, 0, 0, 0};
}
__global__ void k_sentinel(float* __restrict__ out, const int* __restrict__ flags,
                           int ws_mb) {
    if (blockIdx.x == 0 && threadIdx.x == 0)
        out[0] = 1000.0f + (float)ws_mb + 4096.0f * flags[0] + 8192.0f * flags[1];
}

extern "C" void kernel_launch(void* const* d_in, const int* in_sizes, int n_in,
                              void* d_out, int out_size, void* d_ws, size_t ws_size,
                              hipStream_t stream) {
    const void* xm = d_in[0];
    const void* xp = d_in[1];
    const int*  ei = (const int*)d_in[2];
    float* outf = (float*)d_out;

    const size_t NEED = 73019648;
    if (ws_size < NEED) {
        int* flags = (int*)d_ws;
        k_detect<<<1, 256, 0, stream>>>((const uint16_t*)d_in[3], ei, flags);
        int n4 = out_size / 4;
        k_zero_out<<<(n4 + 255) / 256, 256, 0, stream>>>(outf, n4);
        k_sentinel<<<1, 64, 0, stream>>>(outf, flags, (int)(ws_size >> 20));
        return;
    }

    // Layout (73,019,648 B, proven available):
    char* ws = (char*)d_ws;
    int* colg       = (int*)(ws + 0);              //  8,000,000
    int* bmeta      = (int*)(ws + 8000000);        //    400,384 (bucket meta)
    int* bucket_count  = bmeta;                    //  196 ints
    int* bucket_base   = bmeta + 256;              //  197 ints
    int* bucket_cursor = bmeta + 512;              //  196 ints
    int* row_start  = (int*)(ws + 8400384);        //    400,384
    int* flags      = (int*)(ws + 8800768) + 100;
    uint16_t* canonb= (uint16_t*)(ws + 8804864);   //    212,992 (bf16 weights)
    float* biasf    = (float*)(ws + 9017856);      //      1,792 (f32 biases)
    uint16_t* A1    = (uint16_t*)(ws + 9019648);   // 25,600,000
    uint32_t* part  = (uint32_t*)A1;               //  8,000,000 (scratch before A1 is written)
    uint16_t* P     = (uint16_t*)(ws + 34619648);  // 12,800,000 (x cols 0-63 -> P)
    uint16_t* R     = (uint16_t*)(ws + 47419648);  // 12,800,000 (x cols 64-127 -> R)
    uint16_t* Z     = (uint16_t*)(ws + 60219648);  // 12,800,000

    k_detect<<<1, 256, 0, stream>>>((const uint16_t*)d_in[3], ei, flags);
    hipMemsetAsync(bucket_count, 0, 256 * sizeof(int), stream);
    k_prep<<<PREP_PCOUNT + PREP_CANON + (NTOT * 16 + 255) / 256, 256, 0, stream>>>(
        d_in[3], d_in[4], d_in[6], d_in[7], d_in[9], d_in[5], d_in[8], d_in[10],
        xm, xp, ei, canonb, biasf, P, R, bucket_count, flags);
    k_bscan<<<1, 256, 0, stream>>>(bucket_count, bucket_base, bucket_cursor, row_start);
    k_part<<<PREP_PCOUNT, 256, 0, stream>>>(ei, bucket_cursor, part, flags);
    k_sort<<<NB, 256, 0, stream>>>(part, bucket_base, row_start, colg);
    k_agg1<<<NTOT / 16, 256, 0, stream>>>(P, R, row_start, colg, A1);
    k_gemm1<<<(NTOT + 63) / 64, 256, 0, stream>>>(A1, canonb, biasf, P, R);
    k_agg2z<<<NTOT / 32, 256, 0, stream>>>(P, R, row_start, colg, Z);
    k_out<<<G3B + NEDGE * 8 / 256, 256, 0, stream>>>(ei, Z, canonb, biasf, outf, flags);
}

// Round 11
// 373.141 us; speedup vs baseline: 1.0517x; 1.0517x over previous
//
#include <hip/hip_runtime.h>
#include <stdint.h>

#define NMEM 50000
#define NTOT 100000
#define DMEM 96
#define DPRV 128
#define IND  128
#define HID  256
#define LATD 64
#define NEDGE 1000000

// counting-sort CSR build params
#define NB   196   // buckets = ceil(NTOT / 512)
#define VSH  9     // 512 vertices per bucket
#define NBV  512
#define EPB  4096  // edges per block in partition passes

// k_prep role split
#define PREP_PCOUNT 245
#define PREP_CANON  418
// k_out role split
#define G3B 1563

typedef __bf16 v8bf  __attribute__((ext_vector_type(8)));
typedef float  f32x4 __attribute__((ext_vector_type(4)));
typedef float  f32x2 __attribute__((ext_vector_type(2)));

__device__ __forceinline__ float bf2f(uint32_t u) {
    union { uint32_t u; float f; } x; x.u = u << 16; return x.f;
}
__device__ __forceinline__ uint32_t f2bf(float f) {
    union { float f; uint32_t u; } x; x.f = f;
    uint32_t r = x.u + 0x7fffu + ((x.u >> 16) & 1u);
    return r >> 16;
}
__device__ __forceinline__ int ld_ei(const int* ei, int idx, int i64) {
    return i64 ? ei[2 * idx] : ei[idx];
}
// pack 4 f32 -> 4 fp8 e4m3 (OCP on gfx950); RNE in HW
__device__ __forceinline__ uint32_t fp8pk4(float f0, float f1, float f2, float f3) {
    uint32_t w = __builtin_amdgcn_cvt_pk_fp8_f32(f0, f1, 0, false);
    w = __builtin_amdgcn_cvt_pk_fp8_f32(f2, f3, w, true);
    return w;
}
// decode 4 fp8 from u32 and accumulate into a[off..off+3]
__device__ __forceinline__ void fp8x4_acc(uint32_t w, float* a) {
    f32x2 lo = __builtin_amdgcn_cvt_pk_f32_fp8(w, false);
    f32x2 hi = __builtin_amdgcn_cvt_pk_f32_fp8(w, true);
    a[0] += lo.x; a[1] += lo.y; a[2] += hi.x; a[3] += hi.y;
}

// flags[0]=inputs-are-f32, flags[1]=edge-index-is-int64
__global__ void k_detect(const uint16_t* __restrict__ w1l, const int* __restrict__ ei,
                         int* __restrict__ flags) {
    __shared__ int c1, c2;
    if (threadIdx.x == 0) { c1 = 0; c2 = 0; }
    __syncthreads();
    int big = 0;
    for (int i = threadIdx.x; i < 32768; i += 256) {
        float w = bf2f(w1l[i]);
        if (!(w > -2.0f && w < 2.0f)) big++;
    }
    int zhi = 0;
    for (int j = threadIdx.x; j < 2048; j += 256)
        if (ei[2 * j + 1] == 0) zhi++;
    atomicAdd(&c1, big);
    atomicAdd(&c2, zhi);
    __syncthreads();
    if (threadIdx.x == 0) {
        flags[0] = (c1 > 64) ? 1 : 0;
        flags[1] = (c2 > 1024) ? 1 : 0;
    }
}

// k_prep: role-split merge of {pcount | canon | build_x}.
// build_x additionally writes X8 (fp8 copy of the full concat-x row) for
// the agg1 gather: halves gathered bytes AND lines (mean over ~20 nbrs
// washes fp8 quantization noise to ~1%).
__global__ __launch_bounds__(256) void k_prep(const void* w1l, const void* w1r,
                                              const void* w2l, const void* w2r,
                                              const void* wd, const void* b1,
                                              const void* b2, const void* bd,
                                              const void* xm, const void* xp,
                                              const int* __restrict__ ei,
                                              uint16_t* __restrict__ dstw,
                                              float* __restrict__ dstb,
                                              uint16_t* __restrict__ Px,
                                              uint16_t* __restrict__ Rx,
                                              uint8_t* __restrict__ X8,
                                              int* __restrict__ bcount,
                                              const int* __restrict__ flags) {
    __shared__ int h[NB];
    int bid = blockIdx.x;
    int t = threadIdx.x;
    int f32in = flags[0];
    if (bid < PREP_PCOUNT) {
        for (int i = t; i < NB; i += 256) h[i] = 0;
        __syncthreads();
        int i64 = flags[1];
        int j0 = bid * EPB;
        int jend = min(j0 + EPB, NEDGE);
        for (int j = j0 + t; j < jend; j += 256) {
            int p = ld_ei(ei, j, i64), m = ld_ei(ei, NEDGE + j, i64);
            atomicAdd(&h[(NMEM + m) >> VSH], 1);
            atomicAdd(&h[p >> VSH], 1);
        }
        __syncthreads();
        for (int i = t; i < NB; i += 256) atomicAdd(&bcount[i], h[i]);
        return;
    }
    if (bid < PREP_PCOUNT + PREP_CANON) {
        int g = (bid - PREP_PCOUNT) * 256 + t;
        if (g < 106496) {
            const void* src; int off;
            if (g < 65536) { int n = g >> 8, k = g & 255;
                src = (k < 128) ? w1l : w1r; off = n * 128 + (k & 127); }
            else if (g < 81920) { src = w2l; off = g - 65536; }
            else if (g < 98304) { src = w2r; off = g - 81920; }
            else                { src = wd;  off = g - 98304; }
            dstw[g] = f32in ? (uint16_t)f2bf(((const float*)src)[off])
                            : ((const uint16_t*)src)[off];
        } else if (g < 106944) {
            int o = g - 106496;
            const void* src; int off;
            if (o < 256)      { src = b1; off = o; }
            else if (o < 320) { src = b2; off = o - 256; }
            else              { src = bd; off = o - 320; }
            dstb[o] = f32in ? ((const float*)src)[off] : bf2f(((const uint16_t*)src)[off]);
        }
        return;
    }
    int idx = (bid - PREP_PCOUNT - PREP_CANON) * 256 + t;
    if (idx >= NTOT * 16) return;
    int v = idx >> 4, dblk = idx & 15;
    int d0 = dblk * 8;
    union { uint4 q; uint16_t u[8]; } o;
    if (v < NMEM) {
        if (d0 < DMEM) {
            if (f32in) {
                const float* s = (const float*)xm + (size_t)v * DMEM + d0;
                uint4 lo = *(const uint4*)s;
                uint4 hi = *(const uint4*)(s + 4);
                const float* lf = (const float*)&lo;
                const float* hf = (const float*)&hi;
#pragma unroll
                for (int i = 0; i < 4; i++) o.u[i] = (uint16_t)f2bf(lf[i]);
#pragma unroll
                for (int i = 0; i < 4; i++) o.u[4 + i] = (uint16_t)f2bf(hf[i]);
            } else {
                o.q = *(const uint4*)((const uint16_t*)xm + (size_t)v * DMEM + d0);
            }
        } else {
            o.q = (uint4){0, 0, 0, 0};
        }
    } else {
        int vv = v - NMEM;
        if (f32in) {
            const float* s = (const float*)xp + (size_t)vv * DPRV + d0;
            uint4 lo = *(const uint4*)s;
            uint4 hi = *(const uint4*)(s + 4);
            const float* lf = (const float*)&lo;
            const float* hf = (const float*)&hi;
#pragma unroll
            for (int i = 0; i < 4; i++) o.u[i] = (uint16_t)f2bf(lf[i]);
#pragma unroll
            for (int i = 0; i < 4; i++) o.u[4 + i] = (uint16_t)f2bf(hf[i]);
        } else {
            o.q = *(const uint4*)((const uint16_t*)xp + (size_t)vv * DPRV + d0);
        }
    }
    if (d0 < 64) *(uint4*)(Px + (size_t)v * 64 + d0) = o.q;
    else         *(uint4*)(Rx + (size_t)v * 64 + (d0 - 64)) = o.q;
    uint2 x8;
    x8.x = fp8pk4(bf2f(o.u[0]), bf2f(o.u[1]), bf2f(o.u[2]), bf2f(o.u[3]));
    x8.y = fp8pk4(bf2f(o.u[4]), bf2f(o.u[5]), bf2f(o.u[6]), bf2f(o.u[7]));
    *(uint2*)(X8 + (size_t)v * 128 + d0) = x8;
}

__global__ void k_bscan(const int* __restrict__ bcount, int* __restrict__ bbase,
                        int* __restrict__ bcursor, int* __restrict__ row_start) {
    __shared__ int s[256];
    int t = threadIdx.x;
    int v = (t < NB) ? bcount[t] : 0;
    s[t] = v; __syncthreads();
    for (int off = 1; off < 256; off <<= 1) {
        int x = (t >= off) ? s[t - off] : 0;
        __syncthreads();
        s[t] += x;
        __syncthreads();
    }
    if (t < NB) { bbase[t] = s[t] - v; bcursor[t] = s[t] - v; }
    if (t == 0) { bbase[NB] = 2 * NEDGE; row_start[NTOT] = 2 * NEDGE; }
}

__global__ __launch_bounds__(256) void k_part(const int* __restrict__ ei,
                                              int* __restrict__ bcursor,
                                              uint32_t* __restrict__ part,
                                              const int* __restrict__ flags) {
    __shared__ int h[NB], gb[NB], cur[NB];
    int t = threadIdx.x;
    for (int i = t; i < NB; i += 256) { h[i] = 0; cur[i] = 0; }
    __syncthreads();
    int i64 = flags[1];
    int j0 = blockIdx.x * EPB;
    int jend = min(j0 + EPB, NEDGE);
    for (int j = j0 + t; j < jend; j += 256) {
        int p = ld_ei(ei, j, i64), m = ld_ei(ei, NEDGE + j, i64);
        atomicAdd(&h[(NMEM + m) >> VSH], 1);
        atomicAdd(&h[p >> VSH], 1);
    }
    __syncthreads();
    for (int i = t; i < NB; i += 256) gb[i] = atomicAdd(&bcursor[i], h[i]);
    __syncthreads();
    for (int j = j0 + t; j < jend; j += 256) {
        int p = ld_ei(ei, j, i64), m = ld_ei(ei, NEDGE + j, i64);
        int d1 = NMEM + m;
        int d2 = p;
        int b1 = d1 >> VSH, b2 = d2 >> VSH;
        int r1 = atomicAdd(&cur[b1], 1);
        part[gb[b1] + r1] = ((uint32_t)(d1 & (NBV - 1)) << 17) | (uint32_t)p;
        int r2 = atomicAdd(&cur[b2], 1);
        part[gb[b2] + r2] = ((uint32_t)(d2 & (NBV - 1)) << 17) | (uint32_t)(NMEM + m);
    }
}

__global__ __launch_bounds__(256) void k_sort(const uint32_t* __restrict__ part,
                                              const int* __restrict__ bbase,
                                              int* __restrict__ row_start,
                                              int* __restrict__ colg) {
    __shared__ int sa[NBV], sb[NBV];
    int k = blockIdx.x, t = threadIdx.x;
    int base = bbase[k];
    int cnt  = bbase[k + 1] - base;
    for (int i = t; i < NBV; i += 256) sa[i] = 0;
    __syncthreads();
    for (int i = t; i < cnt; i += 256) {
        uint32_t e = part[base + i];
        atomicAdd(&sa[e >> 17], 1);
    }
    __syncthreads();
    int* src = sa; int* dst = sb;
    for (int off = 1; off < NBV; off <<= 1) {
        for (int i = t; i < NBV; i += 256)
            dst[i] = src[i] + (i >= off ? src[i - off] : 0);
        __syncthreads();
        int* tmp = src; src = dst; dst = tmp;
    }
    for (int i = t; i < NBV; i += 256) {
        int excl = (i > 0) ? src[i - 1] : 0;
        dst[i] = excl;
        int gv = (k << VSH) + i;
        if (gv < NTOT) row_start[gv] = base + excl;
    }
    __syncthreads();
    for (int i = t; i < cnt; i += 256) {
        uint32_t e = part[base + i];
        int dloc = (int)(e >> 17);
        int pos = atomicAdd(&dst[dloc], 1);
        colg[base + pos] = (int)(e & 0x1FFFFu);
    }
}

// agg1: A1[v] = mean over nb(v) of x rows, gathered from fp8 X8
// (128B/row = 2 lines vs bf16's 256B/4 lines). R9-verified lane structure:
// 2 vertices/wave, 2 slots x 16 cgs, unroll-2 dual accumulators.
__global__ __launch_bounds__(256) void k_agg1(const uint8_t* __restrict__ X8,
                                              const int* __restrict__ row_start,
                                              const int* __restrict__ colg,
                                              uint16_t* __restrict__ A1) {
    int t = threadIdx.x;
    int half = (t & 63) >> 5;
    int v = blockIdx.x * 8 + (t >> 6) * 2 + half;
    int l32 = t & 31;
    int slot = l32 >> 4, cg = l32 & 15;
    int start = row_start[v], end = row_start[v + 1];
    float a0[8] = {0.f, 0.f, 0.f, 0.f, 0.f, 0.f, 0.f, 0.f};
    float a1[8] = {0.f, 0.f, 0.f, 0.f, 0.f, 0.f, 0.f, 0.f};
    int b = start + slot;
    for (; b + 2 < end; b += 4) {
        int s0 = colg[b], s1 = colg[b + 2];
        uint2 g0 = *(const uint2*)(X8 + (size_t)s0 * 128 + cg * 8);
        uint2 g1 = *(const uint2*)(X8 + (size_t)s1 * 128 + cg * 8);
        fp8x4_acc(g0.x, a0); fp8x4_acc(g0.y, a0 + 4);
        fp8x4_acc(g1.x, a1); fp8x4_acc(g1.y, a1 + 4);
    }
    if (b < end) {
        int s0 = colg[b];
        uint2 g0 = *(const uint2*)(X8 + (size_t)s0 * 128 + cg * 8);
        fp8x4_acc(g0.x, a0); fp8x4_acc(g0.y, a0 + 4);
    }
#pragma unroll
    for (int i = 0; i < 8; i++) {
        a0[i] += a1[i];
        a0[i] += __shfl_xor(a0[i], 16);
    }
    if (slot == 0) {
        float inv = 1.0f / (float)max(end - start, 1);
        union { uint4 q; uint16_t u[8]; } o;
#pragma unroll
        for (int i = 0; i < 8; i++) o.u[i] = (uint16_t)f2bf(a0[i] * inv);
        *(uint4*)(A1 + (size_t)v * 128 + cg * 8) = o.q;
    }
}

// GEMM1 (MFMA, N-split register-B, 64-row tile for occupancy):
// block = 64 rows, 4 waves, LDS 33.8KB -> 4 blocks/CU (R4-verified).
// P output now written as fp8 to P8 (its only consumer is agg2z's mean);
// R output stays bf16, in-place into Rx rows.
__global__ __launch_bounds__(256, 4) void k_gemm1(const uint16_t* __restrict__ A1,
                                                  const uint16_t* __restrict__ canonb,
                                                  const float* __restrict__ biasf,
                                                  const uint16_t* __restrict__ Px,
                                                  uint16_t* __restrict__ Rx,
                                                  uint8_t* __restrict__ P8) {
    __shared__ uint16_t As[64][264];   // 33,792 B; A-panel, then reused as h
    int t = threadIdx.x;
    int w = t >> 6, lane = t & 63;
    int m16 = lane & 15, q = lane >> 4;
    int row0 = blockIdx.x * 64;

    // stage A-panel: 2048 16B chunks, 8 per thread
    uint4 stg[8];
#pragma unroll
    for (int i = 0; i < 8; i++) {
        int c = t + i * 256;
        int row = c >> 5, seg = c & 31;
        int grow = min(row0 + row, NTOT - 1);
        int k0 = seg * 8;
        const uint16_t* src;
        if (k0 < 128)      src = A1 + (size_t)grow * 128 + k0;
        else if (k0 < 192) src = Px + (size_t)grow * 64 + (k0 - 128);
        else               src = Rx + (size_t)grow * 64 + (k0 - 192);
        stg[i] = *(const uint4*)src;
    }
#pragma unroll
    for (int i = 0; i < 8; i++) {
        int c = t + i * 256;
        *(uint4*)&As[c >> 5][(c & 31) * 8] = stg[i];
    }
    __syncthreads();

    // stage 1: h = relu(A @ W1cat^T + b1); 4 passes x 16 cols
    uint32_t hpk[4][4][2];
#pragma unroll
    for (int pn = 0; pn < 4; pn++) {
        int col = w * 64 + pn * 16 + m16;
        v8bf b1[8];
#pragma unroll
        for (int ks = 0; ks < 8; ks++)
            b1[ks] = *(const v8bf*)(canonb + (size_t)col * 256 + ks * 32 + q * 8);
        f32x4 acc[4];
#pragma unroll
        for (int mt = 0; mt < 4; mt++) acc[mt] = (f32x4){0.f, 0.f, 0.f, 0.f};
#pragma unroll
        for (int mt = 0; mt < 4; mt++) {
#pragma unroll
            for (int ks = 0; ks < 8; ks++) {
                v8bf a = *(const v8bf*)&As[mt * 16 + m16][ks * 32 + q * 8];
                acc[mt] = __builtin_amdgcn_mfma_f32_16x16x32_bf16(b1[ks], a, acc[mt], 0, 0, 0);
            }
        }
        int cb = w * 64 + pn * 16 + q * 4;
        f32x4 bb = *(const f32x4*)&biasf[cb];
#pragma unroll
        for (int mt = 0; mt < 4; mt++) {
            float v0 = fmaxf(acc[mt][0] + bb[0], 0.f);
            float v1 = fmaxf(acc[mt][1] + bb[1], 0.f);
            float v2 = fmaxf(acc[mt][2] + bb[2], 0.f);
            float v3 = fmaxf(acc[mt][3] + bb[3], 0.f);
            hpk[pn][mt][0] = f2bf(v0) | (f2bf(v1) << 16);
            hpk[pn][mt][1] = f2bf(v2) | (f2bf(v3) << 16);
        }
        __builtin_amdgcn_sched_barrier(0);
    }
    __syncthreads();   // all As reads done

    // write h into As (uint2 per (pn,mt))
#pragma unroll
    for (int pn = 0; pn < 4; pn++) {
        int cb = w * 64 + pn * 16 + q * 4;
#pragma unroll
        for (int mt = 0; mt < 4; mt++) {
            uint2 v; v.x = hpk[pn][mt][0]; v.y = hpk[pn][mt][1];
            *(uint2*)&As[mt * 16 + m16][cb] = v;
        }
    }
    __syncthreads();

    // stage 2: P = h@W2l^T -> fp8 P8 ; R = h@W2r^T + b2 -> bf16 Rx
    v8bf b2[2][8];
#pragma unroll
    for (int n = 0; n < 2; n++) {
        int c2 = w * 32 + n * 16 + m16;
        const uint16_t* s2 = canonb + (c2 < 64 ? (65536 + c2 * 256) : (81920 + (c2 - 64) * 256));
#pragma unroll
        for (int ks = 0; ks < 8; ks++)
            b2[n][ks] = *(const v8bf*)(s2 + ks * 32 + q * 8);
    }
    f32x4 acc2[4][2];
#pragma unroll
    for (int mt = 0; mt < 4; mt++) {
        acc2[mt][0] = (f32x4){0.f, 0.f, 0.f, 0.f};
        acc2[mt][1] = (f32x4){0.f, 0.f, 0.f, 0.f};
    }
#pragma unroll
    for (int mt = 0; mt < 4; mt++) {
#pragma unroll
        for (int ks = 0; ks < 8; ks++) {
            v8bf hf = *(const v8bf*)&As[mt * 16 + m16][ks * 32 + q * 8];
            acc2[mt][0] = __builtin_amdgcn_mfma_f32_16x16x32_bf16(b2[0][ks], hf, acc2[mt][0], 0, 0, 0);
            acc2[mt][1] = __builtin_amdgcn_mfma_f32_16x16x32_bf16(b2[1][ks], hf, acc2[mt][1], 0, 0, 0);
        }
    }
#pragma unroll
    for (int n = 0; n < 2; n++) {
        int cb = w * 32 + n * 16 + q * 4;
        int isR = cb >= 64;
        int cl = cb - (isR ? 64 : 0);
        if (isR) {
            f32x4 bb = *(const f32x4*)&biasf[256 + cl];
#pragma unroll
            for (int mt = 0; mt < 4; mt++) {
                int row = row0 + mt * 16 + m16;
                if (row < NTOT) {
                    uint2 v;
                    v.x = f2bf(acc2[mt][n][0] + bb[0]) | (f2bf(acc2[mt][n][1] + bb[1]) << 16);
                    v.y = f2bf(acc2[mt][n][2] + bb[2]) | (f2bf(acc2[mt][n][3] + bb[3]) << 16);
                    *(uint2*)(Rx + (size_t)row * 64 + cl) = v;
                }
            }
        } else {
#pragma unroll
            for (int mt = 0; mt < 4; mt++) {
                int row = row0 + mt * 16 + m16;
                if (row < NTOT) {
                    uint32_t pw = fp8pk4(acc2[mt][n][0], acc2[mt][n][1],
                                         acc2[mt][n][2], acc2[mt][n][3]);
                    *(uint32_t*)(P8 + (size_t)row * 64 + cl) = pw;
                }
            }
        }
    }
}

// agg2z: Z[v] = R[v] + mean of P rows over nb(v); P gathered from fp8 P8
// (64B/row = 1 line vs bf16's 2). 2 vertices/wave, 4 slots x 8 cgs,
// unroll-2 dual accumulators. Z written to the retired A1 region.
__global__ __launch_bounds__(256) void k_agg2z(const uint8_t* __restrict__ P8,
                                               const uint16_t* __restrict__ R,
                                               const int* __restrict__ row_start,
                                               const int* __restrict__ colg,
                                               uint16_t* __restrict__ Z) {
    int t = threadIdx.x;
    int half = (t & 63) >> 5;
    int v = blockIdx.x * 8 + (t >> 6) * 2 + half;
    int l32 = t & 31;
    int slot = l32 >> 3, cg = l32 & 7;
    int start = row_start[v], end = row_start[v + 1];
    float a0[8] = {0.f, 0.f, 0.f, 0.f, 0.f, 0.f, 0.f, 0.f};
    float a1[8] = {0.f, 0.f, 0.f, 0.f, 0.f, 0.f, 0.f, 0.f};
    int b = start + slot;
    for (; b + 4 < end; b += 8) {
        int s0 = colg[b], s1 = colg[b + 4];
        uint2 g0 = *(const uint2*)(P8 + (size_t)s0 * 64 + cg * 8);
        uint2 g1 = *(const uint2*)(P8 + (size_t)s1 * 64 + cg * 8);
        fp8x4_acc(g0.x, a0); fp8x4_acc(g0.y, a0 + 4);
        fp8x4_acc(g1.x, a1); fp8x4_acc(g1.y, a1 + 4);
    }
    if (b < end) {
        int s0 = colg[b];
        uint2 g0 = *(const uint2*)(P8 + (size_t)s0 * 64 + cg * 8);
        fp8x4_acc(g0.x, a0); fp8x4_acc(g0.y, a0 + 4);
    }
#pragma unroll
    for (int i = 0; i < 8; i++) {
        a0[i] += a1[i];
        a0[i] += __shfl_xor(a0[i], 8);
        a0[i] += __shfl_xor(a0[i], 16);
    }
    if (slot == 0) {
        float inv = 1.0f / (float)max(end - start, 1);
        union { uint4 q; uint16_t u[8]; } rr, o;
        rr.q = *(const uint4*)(R + (size_t)v * 64 + cg * 8);
#pragma unroll
        for (int i = 0; i < 8; i++)
            o.u[i] = (uint16_t)f2bf(a0[i] * inv + bf2f(rr.u[i]));
        *(uint4*)(Z + (size_t)v * 64 + cg * 8) = o.q;
    }
}

// k_out: role-split merge of {gemm3 | logits}.
__global__ __launch_bounds__(256, 4) void k_out(const int* __restrict__ ei,
                                                const uint16_t* __restrict__ Z,
                                                const uint16_t* __restrict__ canonb,
                                                const float* __restrict__ biasf,
                                                float* __restrict__ outf,
                                                const int* __restrict__ flags) {
    int bid = blockIdx.x;
    if (bid < G3B) {
        int wave = threadIdx.x >> 6, lane = threadIdx.x & 63;
        int m16 = lane & 15, quad = lane >> 4;
        int row0 = (bid * 4 + wave) * 16;
        int arow = min(row0 + m16, NTOT - 1);
        v8bf a0 = *(const v8bf*)(Z + (size_t)arow * 64 + quad * 8);
        v8bf a1 = *(const v8bf*)(Z + (size_t)arow * 64 + 32 + quad * 8);
        v8bf b0[8], b1[8];
#pragma unroll
        for (int nt = 0; nt < 8; nt++) {
            b0[nt] = *(const v8bf*)(canonb + 98304 + (size_t)(nt * 16 + m16) * 64 + quad * 8);
            b1[nt] = *(const v8bf*)(canonb + 98304 + (size_t)(nt * 16 + m16) * 64 + 32 + quad * 8);
        }
        f32x4 acc[8];
#pragma unroll
        for (int i = 0; i < 8; i++) acc[i] = (f32x4){0.f, 0.f, 0.f, 0.f};
#pragma unroll
        for (int nt = 0; nt < 8; nt++) {
            acc[nt] = __builtin_amdgcn_mfma_f32_16x16x32_bf16(a0, b0[nt], acc[nt], 0, 0, 0);
            acc[nt] = __builtin_amdgcn_mfma_f32_16x16x32_bf16(a1, b1[nt], acc[nt], 0, 0, 0);
        }
#pragma unroll
        for (int nt = 0; nt < 8; nt++) {
            int col = nt * 16 + m16;
            float bia = biasf[320 + col];
#pragma unroll
            for (int r = 0; r < 4; r++) {
                int row = row0 + quad * 4 + r;
                if (row < NTOT) outf[(size_t)row * 128 + col] = acc[nt][r] + bia;
            }
        }
        return;
    }
    int t = (bid - G3B) * 256 + threadIdx.x;
    int j = t >> 3, sub = t & 7;
    if (j >= NEDGE) return;
    int i64 = flags[1];
    int p = ld_ei(ei, j, i64), m = ld_ei(ei, NEDGE + j, i64);
    union { uint4 q; uint16_t u[8]; } a, b;
    a.q = *(const uint4*)(Z + (size_t)(NMEM + p) * 64 + sub * 8);
    b.q = *(const uint4*)(Z + (size_t)m * 64 + sub * 8);
    float d = 0.f;
#pragma unroll
    for (int i = 0; i < 8; i++) d += bf2f(a.u[i]) * bf2f(b.u[i]);
    d += __shfl_xor(d, 1);
    d += __shfl_xor(d, 2);
    d += __shfl_xor(d, 4);
    if (sub == 0) outf[12800000 + j] = d;
}

// Sentinel path (ws too small).
__global__ void k_zero_out(float* __restrict__ out, int n4) {
    int i = blockIdx.x * 256 + threadIdx.x;
    if (i < n4) ((uint4*)out)[i] = (uint4){0, 0, 0, 0};
}
__global__ void k_sentinel(float* __restrict__ out, const int* __restrict__ flags,
                           int ws_mb) {
    if (blockIdx.x == 0 && threadIdx.x == 0)
        out[0] = 1000.0f + (float)ws_mb + 4096.0f * flags[0] + 8192.0f * flags[1];
}

extern "C" void kernel_launch(void* const* d_in, const int* in_sizes, int n_in,
                              void* d_out, int out_size, void* d_ws, size_t ws_size,
                              hipStream_t stream) {
    const void* xm = d_in[0];
    const void* xp = d_in[1];
    const int*  ei = (const int*)d_in[2];
    float* outf = (float*)d_out;

    const size_t NEED = 73019648;
    if (ws_size < NEED) {
        int* flags = (int*)d_ws;
        k_detect<<<1, 256, 0, stream>>>((const uint16_t*)d_in[3], ei, flags);
        int n4 = out_size / 4;
        k_zero_out<<<(n4 + 255) / 256, 256, 0, stream>>>(outf, n4);
        k_sentinel<<<1, 64, 0, stream>>>(outf, flags, (int)(ws_size >> 20));
        return;
    }

    // Layout (73,019,648 B). Lifetime-based aliasing:
    //   A1 region: part scratch (pre-agg1) -> A1 (agg1->gemm1) -> Z (agg2z->out)
    //   old-Z region: X8 fp8 x-copy (prep->agg1) -> P8 fp8 P (gemm1->agg2z)
    char* ws = (char*)d_ws;
    int* colg       = (int*)(ws + 0);              //  8,000,000
    int* bmeta      = (int*)(ws + 8000000);        //    400,384 (bucket meta)
    int* bucket_count  = bmeta;                    //  196 ints
    int* bucket_base   = bmeta + 256;              //  197 ints
    int* bucket_cursor = bmeta + 512;              //  196 ints
    int* row_start  = (int*)(ws + 8400384);        //    400,384
    int* flags      = (int*)(ws + 8800768) + 100;
    uint16_t* canonb= (uint16_t*)(ws + 8804864);   //    212,992 (bf16 weights)
    float* biasf    = (float*)(ws + 9017856);      //      1,792 (f32 biases)
    uint16_t* A1    = (uint16_t*)(ws + 9019648);   // 25,600,000 (bf16 [NTOT][128])
    uint32_t* part  = (uint32_t*)A1;               //  8,000,000 (dead before agg1)
    uint16_t* Zn    = (uint16_t*)(ws + 9019648);   // 12,800,000 (Z, after A1 dies)
    uint16_t* Px    = (uint16_t*)(ws + 34619648);  // 12,800,000 (x cols 0-63, bf16)
    uint16_t* Rx    = (uint16_t*)(ws + 47419648);  // 12,800,000 (x cols 64-127 -> R out)
    uint8_t*  X8    = (uint8_t*)(ws + 60219648);   // 12,800,000 (fp8 x, prep->agg1)
    uint8_t*  P8    = (uint8_t*)(ws + 60219648);   //  6,400,000 (fp8 P, gemm1->agg2z)

    k_detect<<<1, 256, 0, stream>>>((const uint16_t*)d_in[3], ei, flags);
    hipMemsetAsync(bucket_count, 0, 256 * sizeof(int), stream);
    k_prep<<<PREP_PCOUNT + PREP_CANON + (NTOT * 16 + 255) / 256, 256, 0, stream>>>(
        d_in[3], d_in[4], d_in[6], d_in[7], d_in[9], d_in[5], d_in[8], d_in[10],
        xm, xp, ei, canonb, biasf, Px, Rx, X8, bucket_count, flags);
    k_bscan<<<1, 256, 0, stream>>>(bucket_count, bucket_base, bucket_cursor, row_start);
    k_part<<<PREP_PCOUNT, 256, 0, stream>>>(ei, bucket_cursor, part, flags);
    k_sort<<<NB, 256, 0, stream>>>(part, bucket_base, row_start, colg);
    k_agg1<<<NTOT / 8, 256, 0, stream>>>(X8, row_start, colg, A1);
    k_gemm1<<<(NTOT + 63) / 64, 256, 0, stream>>>(A1, canonb, biasf, Px, Rx, P8);
    k_agg2z<<<NTOT / 8, 256, 0, stream>>>(P8, Rx, row_start, colg, Zn);
    k_out<<<G3B + NEDGE * 8 / 256, 256, 0, stream>>>(ei, Zn, canonb, biasf, outf, flags);
}